// Round 6
// baseline (306.552 us; speedup 1.0000x reference)
//
#include <hip/hip_runtime.h>

constexpr int D = 128;
constexpr int H = 256;
constexpr float EPS = 1e-5f;

typedef __attribute__((ext_vector_type(8))) __bf16  bf16x8;   // 4 VGPRs
typedef __attribute__((ext_vector_type(4))) float   f32x4;

static __device__ __forceinline__ unsigned short f2bfu(float f) {
    unsigned u = __float_as_uint(f);
    return (unsigned short)((u + 0x7FFFu + ((u >> 16) & 1u)) >> 16);   // RNE
}
static __device__ __forceinline__ float bf2f(unsigned short u) {
    return __uint_as_float((unsigned)u << 16);
}

static __device__ __forceinline__ f32x4 mfma16x16x32(bf16x8 a, bf16x8 b, f32x4 c) {
    return __builtin_amdgcn_mfma_f32_16x16x32_bf16(a, b, c, 0, 0, 0);
}

// ---------------------------------------------------------------------------
// Pack W (K x Ncols fp32 row-major) into MFMA B-fragment order, bf16:
// Wp[((j*nt + t)*64 + lane)*8 + i] = bf16(W[(32t + (lane>>4)*8 + i)*Ncols + 16j + (lane&15)])
// ---------------------------------------------------------------------------
__global__ __launch_bounds__(256) void pack_w_kernel(
    const float* __restrict__ W, unsigned short* __restrict__ Wp, int K, int Ncols)
{
    int e = blockIdx.x * 256 + threadIdx.x;
    if (e >= K * Ncols) return;
    int i  = e & 7;
    int l  = (e >> 3) & 63;
    int jt = e >> 9;
    int nt = K >> 5;
    int j  = jt / nt;
    int t  = jt - j * nt;
    int k  = 32 * t + ((l >> 4) << 3) + i;
    int c  = 16 * j + (l & 15);
    Wp[e] = f2bfu(W[(size_t)k * Ncols + c]);
}

// ---------------------------------------------------------------------------
// conv = LN2( relu(LN1(x@W1 + b1)) @ W2 + b2 ), bf16 MFMA, output bf16.
// 128 rows/block, 4 waves, each wave owns 32 rows = TWO 16-row A-tiles that
// share every B-fragment load (halves L2 weight traffic vs 16 rows/wave).
// No barriers: Hs regions are wave-private.
// ---------------------------------------------------------------------------
__global__ __launch_bounds__(256) void conv_mlp_mfma(
    const float* __restrict__ x,
    const unsigned short* __restrict__ W1p, const float* __restrict__ b1,
    const float* __restrict__ g1, const float* __restrict__ be1,
    const unsigned short* __restrict__ W2p, const float* __restrict__ b2,
    const float* __restrict__ g2, const float* __restrict__ be2,
    unsigned short* __restrict__ convb, int N)
{
    __shared__ unsigned short Hs[128 * 256];   // 64 KB bf16, XOR-swizzled rows
    const int wv   = threadIdx.x >> 6;
    const int lane = threadIdx.x & 63;
    const int rrow = lane & 15;    // A row / B,C col index
    const int kgrp = lane >> 4;    // input k-group / C row-group
    const int r0   = blockIdx.x * 128 + wv * 32;

    // ---- A fragments for GEMM1, 2 tiles, direct from global x (fp32->bf16) ----
    bf16x8 A1[2][4];
    #pragma unroll
    for (int u = 0; u < 2; ++u) {
        int arow = r0 + u * 16 + rrow; if (arow >= N) arow = N - 1;
        const float* xr = x + (size_t)arow * D + kgrp * 8;
        #pragma unroll
        for (int t = 0; t < 4; ++t) {
            float4 fa = *(const float4*)(xr + t * 32);
            float4 fb = *(const float4*)(xr + t * 32 + 4);
            bf16x8 a;
            a[0] = (__bf16)fa.x; a[1] = (__bf16)fa.y; a[2] = (__bf16)fa.z; a[3] = (__bf16)fa.w;
            a[4] = (__bf16)fb.x; a[5] = (__bf16)fb.y; a[6] = (__bf16)fb.z; a[7] = (__bf16)fb.w;
            A1[u][t] = a;
        }
    }

    // ---- GEMM1: S(2x16x256), 16 col-tiles x 4 K-tiles, B shared by 2 tiles ----
    f32x4 acc[2][16];
    #pragma unroll
    for (int u = 0; u < 2; ++u)
        #pragma unroll
        for (int j = 0; j < 16; ++j) acc[u][j] = (f32x4){0.f, 0.f, 0.f, 0.f};
    const bf16x8* w1f = (const bf16x8*)W1p;
    #pragma unroll
    for (int j = 0; j < 16; ++j) {
        #pragma unroll
        for (int t = 0; t < 4; ++t) {
            bf16x8 B = w1f[(j * 4 + t) * 64 + lane];
            acc[0][j] = mfma16x16x32(A1[0][t], B, acc[0][j]);
            acc[1][j] = mfma16x16x32(A1[1][t], B, acc[1][j]);
        }
    }

    // ---- LN1 params (shared by both tiles) ----
    float b1r[16], g1r[16], be1r[16];
    #pragma unroll
    for (int j = 0; j < 16; ++j) {
        int c = 16 * j + rrow;
        b1r[j] = b1[c]; g1r[j] = g1[c]; be1r[j] = be1[c];
    }

    // ---- bias + LN1 + relu -> Hs (bf16, swizzled), per tile ----
    #pragma unroll
    for (int u = 0; u < 2; ++u) {
        float s1[4] = {0,0,0,0}, s2[4] = {0,0,0,0};
        #pragma unroll
        for (int j = 0; j < 16; ++j) {
            #pragma unroll
            for (int r = 0; r < 4; ++r) {
                float v = acc[u][j][r] + b1r[j];
                acc[u][j][r] = v;
                s1[r] += v; s2[r] += v * v;
            }
        }
        #pragma unroll
        for (int m = 1; m < 16; m <<= 1) {
            #pragma unroll
            for (int r = 0; r < 4; ++r) {
                s1[r] += __shfl_xor(s1[r], m);
                s2[r] += __shfl_xor(s2[r], m);
            }
        }
        #pragma unroll
        for (int r = 0; r < 4; ++r) {
            float mu  = s1[r] * (1.f / H);
            float var = s2[r] * (1.f / H) - mu * mu;
            float rs  = rsqrtf(var + EPS);
            int row = wv * 32 + u * 16 + kgrp * 4 + r;      // block-local row
            #pragma unroll
            for (int j = 0; j < 16; ++j) {
                float h = fmaxf((acc[u][j][r] - mu) * rs * g1r[j] + be1r[j], 0.f);
                int byte = (row << 9) + ((16 * j + rrow) << 1);
                byte ^= (row & 15) << 4;
                *(unsigned short*)((char*)Hs + byte) = f2bfu(h);
            }
        }
    }

    // ---- A fragments for GEMM2 from Hs (swizzled 16B reads) ----
    bf16x8 A2[2][8];
    #pragma unroll
    for (int u = 0; u < 2; ++u) {
        int row = wv * 32 + u * 16 + rrow;
        #pragma unroll
        for (int t = 0; t < 8; ++t) {
            int byte = (row << 9) + ((t * 32 + kgrp * 8) << 1);
            byte ^= (row & 15) << 4;
            A2[u][t] = *(const bf16x8*)((const char*)Hs + byte);
        }
    }

    // ---- GEMM2: C(2x16x128), 8 col-tiles x 8 K-tiles, B shared by 2 tiles ----
    f32x4 acc2[2][8];
    #pragma unroll
    for (int u = 0; u < 2; ++u)
        #pragma unroll
        for (int j = 0; j < 8; ++j) acc2[u][j] = (f32x4){0.f, 0.f, 0.f, 0.f};
    const bf16x8* w2f = (const bf16x8*)W2p;
    #pragma unroll
    for (int j = 0; j < 8; ++j) {
        #pragma unroll
        for (int t = 0; t < 8; ++t) {
            bf16x8 B = w2f[(j * 8 + t) * 64 + lane];
            acc2[0][j] = mfma16x16x32(A2[0][t], B, acc2[0][j]);
            acc2[1][j] = mfma16x16x32(A2[1][t], B, acc2[1][j]);
        }
    }

    // ---- LN2 params ----
    float b2r[8], g2r[8], be2r[8];
    #pragma unroll
    for (int j = 0; j < 8; ++j) {
        int c = 16 * j + rrow;
        b2r[j] = b2[c]; g2r[j] = g2[c]; be2r[j] = be2[c];
    }

    // ---- bias + LN2 + store conv (bf16), per tile ----
    #pragma unroll
    for (int u = 0; u < 2; ++u) {
        float u1[4] = {0,0,0,0}, u2[4] = {0,0,0,0};
        #pragma unroll
        for (int j = 0; j < 8; ++j) {
            #pragma unroll
            for (int r = 0; r < 4; ++r) {
                float v = acc2[u][j][r] + b2r[j];
                acc2[u][j][r] = v;
                u1[r] += v; u2[r] += v * v;
            }
        }
        #pragma unroll
        for (int m = 1; m < 16; m <<= 1) {
            #pragma unroll
            for (int r = 0; r < 4; ++r) {
                u1[r] += __shfl_xor(u1[r], m);
                u2[r] += __shfl_xor(u2[r], m);
            }
        }
        #pragma unroll
        for (int r = 0; r < 4; ++r) {
            float mu  = u1[r] * (1.f / D);
            float var = u2[r] * (1.f / D) - mu * mu;
            float rs  = rsqrtf(var + EPS);
            int grow = r0 + u * 16 + kgrp * 4 + r;
            if (grow < N) {
                #pragma unroll
                for (int j = 0; j < 8; ++j) {
                    float o = (acc2[u][j][r] - mu) * rs * g2r[j] + be2r[j];
                    convb[(size_t)grow * D + 16 * j + rrow] = f2bfu(o);
                }
            }
        }
    }
}

// ---------------------------------------------------------------------------
// CSR build: zero -> histogram -> 3-step exclusive scan -> fill permutation
// ---------------------------------------------------------------------------
__global__ __launch_bounds__(256) void zero_int_kernel(int* __restrict__ p, int n) {
    int i = blockIdx.x * blockDim.x + threadIdx.x;
    if (i < n) p[i] = 0;
}

__global__ __launch_bounds__(256) void hist_kernel(
    const int* __restrict__ eidx, int* __restrict__ counts, int E)
{
    int e = blockIdx.x * blockDim.x + threadIdx.x;
    if (e < E) atomicAdd(&counts[eidx[e]], 1);
}

__global__ __launch_bounds__(256) void scan1_kernel(
    const int* __restrict__ counts, int* __restrict__ row_start,
    int* __restrict__ bsums, int N)
{
    __shared__ int sd[256];
    int t  = threadIdx.x;
    int i0 = blockIdx.x * 1024 + t * 4;
    int c0 = (i0+0 < N) ? counts[i0+0] : 0;
    int c1 = (i0+1 < N) ? counts[i0+1] : 0;
    int c2 = (i0+2 < N) ? counts[i0+2] : 0;
    int c3 = (i0+3 < N) ? counts[i0+3] : 0;
    int s  = c0 + c1 + c2 + c3;
    sd[t] = s;
    __syncthreads();
    #pragma unroll
    for (int off = 1; off < 256; off <<= 1) {
        int v = (t >= off) ? sd[t - off] : 0;
        __syncthreads();
        sd[t] += v;
        __syncthreads();
    }
    int ex = sd[t] - s;
    if (i0+0 < N) row_start[i0+0] = ex;
    if (i0+1 < N) row_start[i0+1] = ex + c0;
    if (i0+2 < N) row_start[i0+2] = ex + c0 + c1;
    if (i0+3 < N) row_start[i0+3] = ex + c0 + c1 + c2;
    if (t == 255) bsums[blockIdx.x] = sd[255];
}

__global__ __launch_bounds__(128) void scan2_kernel(int* __restrict__ bsums, int NB)
{
    __shared__ int sd[128];
    int t = threadIdx.x;
    int v = (t < NB) ? bsums[t] : 0;
    sd[t] = v;
    __syncthreads();
    #pragma unroll
    for (int off = 1; off < 128; off <<= 1) {
        int u = (t >= off) ? sd[t - off] : 0;
        __syncthreads();
        sd[t] += u;
        __syncthreads();
    }
    if (t < NB) bsums[t] = sd[t] - v;
}

__global__ __launch_bounds__(256) void scan3_kernel(
    int* __restrict__ row_start, const int* __restrict__ bsums,
    int* __restrict__ cursor, int N)
{
    int i = blockIdx.x * blockDim.x + threadIdx.x;
    if (i < N) {
        int r = row_start[i] + bsums[i >> 10];
        row_start[i] = r;
        cursor[i]    = r;
    }
}

// edat[p] = {edge id, dst}
__global__ __launch_bounds__(256) void fill_kernel(
    const int* __restrict__ eidx, int* __restrict__ cursor,
    int2* __restrict__ edat, int E)
{
    int e = blockIdx.x * blockDim.x + threadIdx.x;
    if (e < E) {
        int s = eidx[e];
        int p = atomicAdd(&cursor[s], 1);
        edat[p] = make_int2(e, eidx[E + e]);
    }
}

// ---------------------------------------------------------------------------
// out[v] = LN( x[v] + sum_{e: src=v} conv_bf16[dst]*eattr[e] )
// One wave per node; each 32-lane HALF processes its own edge stream with
// float4/ushort4 loads -> 4 independent edge chains in flight per wave.
// ---------------------------------------------------------------------------
__global__ __launch_bounds__(256) void gather_ln_kernel(
    const float* __restrict__ x, const unsigned short* __restrict__ convb,
    const float* __restrict__ eattr,
    const int* __restrict__ row_start, const int2* __restrict__ edat,
    const float* __restrict__ g, const float* __restrict__ b,
    float* __restrict__ out, int N, int E)
{
    int node = blockIdx.x * 4 + (threadIdx.x >> 6);
    if (node >= N) return;
    int lane = threadIdx.x & 63;
    int half = lane >> 5;           // 0 or 1: which edge stream
    int c4   = (lane & 31) * 4;     // 4 consecutive cols per lane

    float4 acc = make_float4(0.f, 0.f, 0.f, 0.f);
    int je = (node + 1 < N) ? row_start[node + 1] : E;
    int j  = row_start[node] + half;

    for (; j + 2 < je; j += 4) {
        int2 ea = edat[j];
        int2 eb = edat[j + 2];
        ushort4 ca = *(const ushort4*)(convb + (size_t)ea.y * D + c4);
        float4  aa = *(const float4*) (eattr + (size_t)ea.x * D + c4);
        ushort4 cb = *(const ushort4*)(convb + (size_t)eb.y * D + c4);
        float4  ab = *(const float4*) (eattr + (size_t)eb.x * D + c4);
        acc.x += bf2f(ca.x) * aa.x; acc.y += bf2f(ca.y) * aa.y;
        acc.z += bf2f(ca.z) * aa.z; acc.w += bf2f(ca.w) * aa.w;
        acc.x += bf2f(cb.x) * ab.x; acc.y += bf2f(cb.y) * ab.y;
        acc.z += bf2f(cb.z) * ab.z; acc.w += bf2f(cb.w) * ab.w;
    }
    if (j < je) {
        int2 ea = edat[j];
        ushort4 ca = *(const ushort4*)(convb + (size_t)ea.y * D + c4);
        float4  aa = *(const float4*) (eattr + (size_t)ea.x * D + c4);
        acc.x += bf2f(ca.x) * aa.x; acc.y += bf2f(ca.y) * aa.y;
        acc.z += bf2f(ca.z) * aa.z; acc.w += bf2f(ca.w) * aa.w;
    }

    if (half == 0) {
        float4 xv = *(const float4*)(x + (size_t)node * D + c4);
        acc.x += xv.x; acc.y += xv.y; acc.z += xv.z; acc.w += xv.w;
    }
    acc.x += __shfl_xor(acc.x, 32);
    acc.y += __shfl_xor(acc.y, 32);
    acc.z += __shfl_xor(acc.z, 32);
    acc.w += __shfl_xor(acc.w, 32);

    float s1 = acc.x + acc.y + acc.z + acc.w;
    float s2 = acc.x*acc.x + acc.y*acc.y + acc.z*acc.z + acc.w*acc.w;
    #pragma unroll
    for (int o = 1; o < 32; o <<= 1) {
        s1 += __shfl_xor(s1, o);
        s2 += __shfl_xor(s2, o);
    }
    float mu  = s1 * (1.f / D);
    float var = s2 * (1.f / D) - mu * mu;
    float rs  = rsqrtf(var + EPS);
    if (half == 0) {
        float4 gv = *(const float4*)(g + c4);
        float4 bv = *(const float4*)(b + c4);
        float4 o4;
        o4.x = (acc.x - mu) * rs * gv.x + bv.x;
        o4.y = (acc.y - mu) * rs * gv.y + bv.y;
        o4.z = (acc.z - mu) * rs * gv.z + bv.z;
        o4.w = (acc.w - mu) * rs * gv.w + bv.w;
        *(float4*)(out + (size_t)node * D + c4) = o4;
    }
}

extern "C" void kernel_launch(void* const* d_in, const int* in_sizes, int n_in,
                              void* d_out, int out_size, void* d_ws, size_t ws_size,
                              hipStream_t stream) {
    const float* x     = (const float*)d_in[0];
    const int*   eidx  = (const int*)  d_in[1];
    const float* eattr = (const float*)d_in[2];
    const float* W1    = (const float*)d_in[3];
    const float* b1    = (const float*)d_in[4];
    const float* g1    = (const float*)d_in[5];
    const float* be1   = (const float*)d_in[6];
    const float* W2    = (const float*)d_in[7];
    const float* b2    = (const float*)d_in[8];
    const float* g2    = (const float*)d_in[9];
    const float* be2   = (const float*)d_in[10];
    const float* g_out = (const float*)d_in[11];
    const float* b_out = (const float*)d_in[12];

    const int N = in_sizes[0] / D;   // 100000
    const int E = in_sizes[1] / 2;   // 640000

    float* out = (float*)d_out;

    // workspace layout (256B aligned)
    auto align_up = [](size_t v) { return (v + 255) & ~(size_t)255; };
    size_t convB = align_up((size_t)N * D * sizeof(unsigned short));  // 25.6 MB
    size_t cntB  = align_up((size_t)N * sizeof(int));
    size_t rsB   = align_up((size_t)N * sizeof(int));
    size_t bsB   = align_up(128 * sizeof(int));
    size_t edB   = align_up((size_t)E * sizeof(int2));                // 5.12 MB
    size_t w1B   = align_up((size_t)D * H * sizeof(unsigned short));  // 64 KB

    char* w = (char*)d_ws;
    unsigned short* convb     = (unsigned short*)(w);
    int*            counts    = (int*)(w + convB);                 // reused as cursor
    int*            row_start = (int*)(w + convB + cntB);
    int*            bsums     = (int*)(w + convB + cntB + rsB);
    int2*           edat      = (int2*)(w + convB + cntB + rsB + bsB);
    unsigned short* W1p       = (unsigned short*)(w + convB + cntB + rsB + bsB + edB);
    unsigned short* W2p       = (unsigned short*)(w + convB + cntB + rsB + bsB + edB + w1B);

    // 1) pack weights into MFMA fragment order (bf16)
    pack_w_kernel<<<(D * H + 255) / 256, 256, 0, stream>>>(W1, W1p, D, H);
    pack_w_kernel<<<(H * D + 255) / 256, 256, 0, stream>>>(W2, W2p, H, D);

    // 2) conv = MLP(x) via bf16 MFMA (128 rows/block)
    conv_mlp_mfma<<<(N + 127) / 128, 256, 0, stream>>>(
        x, W1p, b1, g1, be1, W2p, b2, g2, be2, convb, N);

    // 3) CSR build
    zero_int_kernel<<<(N + 255) / 256, 256, 0, stream>>>(counts, N);
    hist_kernel<<<(E + 255) / 256, 256, 0, stream>>>(eidx, counts, E);
    int NB = (N + 1023) / 1024;
    scan1_kernel<<<NB, 256, 0, stream>>>(counts, row_start, bsums, N);
    scan2_kernel<<<1, 128, 0, stream>>>(bsums, NB);
    scan3_kernel<<<(N + 255) / 256, 256, 0, stream>>>(row_start, bsums, counts, N);
    fill_kernel<<<(E + 255) / 256, 256, 0, stream>>>(eidx, counts, edat, E);

    // 4) gather + final LN
    gather_ln_kernel<<<(N + 3) / 4, 256, 0, stream>>>(
        x, convb, eattr, row_start, edat, g_out, b_out, out, N, E);
}